// Round 31
// baseline (105.461 us; speedup 1.0000x reference)
//
#include <hip/hip_runtime.h>
#include <hip/hip_bf16.h>
#include <stdint.h>
#include <math.h>

typedef unsigned short u16;
typedef __attribute__((ext_vector_type(8))) short bf16x8;   // 8 bf16 = 4 VGPR MFMA frag
typedef __attribute__((ext_vector_type(4))) float f32x4;    // MFMA accumulator frag

#define MFMA16(a,b,c) __builtin_amdgcn_mfma_f32_16x16x32_bf16((a),(b),(c),0,0,0)

__device__ __forceinline__ u16 f2bf(float f) {
    union { float f; uint32_t u; } v; v.f = f;
    return (u16)((v.u + 0x7FFFu + ((v.u >> 16) & 1u)) >> 16);   // RNE
}

__device__ __forceinline__ uint32_t cvt_pk_bf16(float lo, float hi) {
    uint32_t r;
    asm("v_cvt_pk_bf16_f32 %0, %1, %2" : "=v"(r) : "v"(lo), "v"(hi));
    return r;
}

// ---------- fused prep: x->bf16 | Wqkv^T->bf16 | Wproj^T->bf16 (one dispatch) ----------
__global__ void k_prep(const float* __restrict__ x,
                       const float* __restrict__ Wqkv,
                       const float* __restrict__ Wproj,
                       u16* __restrict__ xb,
                       u16* __restrict__ WqkvT,
                       u16* __restrict__ WprojT)
{
    const int bid = blockIdx.x, tid = threadIdx.x;
    if (bid < 4096) {
        int i = (bid * 256 + tid) * 4;
        f32x4 v = *(const f32x4*)(x + i);
        uint64_t p = (uint64_t)f2bf(v[0]) | ((uint64_t)f2bf(v[1]) << 16)
                   | ((uint64_t)f2bf(v[2]) << 32) | ((uint64_t)f2bf(v[3]) << 48);
        *(uint64_t*)(xb + i) = p;
    } else if (bid < 5632) {
        int id = (bid - 4096) * 256 + tid;
        int n = id % 3072, kc = id / 3072;
        bf16x8 o;
#pragma unroll
        for (int i = 0; i < 8; ++i)
            o[i] = (short)f2bf(Wqkv[(size_t)(kc * 8 + i) * 3072 + n]);
        *(bf16x8*)(WqkvT + (size_t)n * 1024 + kc * 8) = o;
    } else {
        int id = (bid - 5632) * 256 + tid;
        int n = id % 1024, kc = id / 1024;
        bf16x8 o;
#pragma unroll
        for (int i = 0; i < 8; ++i)
            o[i] = (short)f2bf(Wproj[(size_t)(kc * 8 + i) * 1024 + n]);
        *(bf16x8*)(WprojT + (size_t)n * 1024 + kc * 8) = o;
    }
}

// ---------------- bf16 MFMA GEMM body (r10-verified structure) ----------------
// BM=128, BN=32*NREP, BK=32. 4 waves (2x2), wave tile 64 x 16*NREP.
// 3-deep LDS buffers, counted vmcnt (tile k+2 in flight across barrier).
// XOR chunk swizzle on GLOBAL source + ds_read addr (both-sides, LDS linear).
// MODE 0: scatter to qkv bf16 (q scaled 0.125*log2e); V third TRANSPOSED [bh][d][t].
// MODE 1: fp32 row-major + bias.
template<int NREP, int MODE>
__device__ __forceinline__ void gemm_body(
    const u16* __restrict__ A, const u16* __restrict__ Bt,
    const float* __restrict__ bias,
    u16* __restrict__ outQKV, float* __restrict__ outF,
    int M, int N, int tileId, int K)
{
    constexpr int BN = 32 * NREP;
    constexpr int WN = 16 * NREP;
    constexpr int BSLOTS = NREP / 2;
    __shared__ __align__(16) u16 As[3][128 * 32];
    __shared__ __align__(16) u16 Bs[3][BN * 32];
    const int tid = threadIdx.x;
    const int nbx = N / BN;
    const int bm = tileId / nbx, bn = tileId % nbx;
    const int m0 = bm << 7, n0 = bn * BN;
    const int l = tid & 63, w = tid >> 6;
    const int wr = w >> 1, wc = w & 1;
    const int kl = l >> 4, lr = l & 15;

    const u16* Ag = A + (size_t)m0 * K;
    const u16* Bg = Bt + (size_t)n0 * K;

    int a_src[2], a_dst[2];
#pragma unroll
    for (int s = 0; s < 2; ++s) {
        int cb = w * 128 + s * 64;
        int c = cb + l;
        int r = c >> 2, kc = c & 3;
        a_src[s] = r * K + ((kc ^ ((r >> 1) & 3)) << 3);
        a_dst[s] = cb << 3;
    }
    int b_src[BSLOTS], b_dst[BSLOTS];
#pragma unroll
    for (int s = 0; s < BSLOTS; ++s) {
        int cb = (w * BSLOTS + s) * 64;
        int c = cb + l;
        int r = c >> 2, kc = c & 3;
        b_src[s] = r * K + ((kc ^ ((r >> 1) & 3)) << 3);
        b_dst[s] = cb << 3;
    }

    int ra[4], rb[NREP];
#pragma unroll
    for (int m = 0; m < 4; ++m) {
        int row = wr * 64 + m * 16 + lr;
        ra[m] = row * 32 + (((kl ^ (row >> 1)) & 3) << 3);
    }
#pragma unroll
    for (int n = 0; n < NREP; ++n) {
        int row = wc * WN + n * 16 + lr;
        rb[n] = row * 32 + (((kl ^ (row >> 1)) & 3) << 3);
    }

    f32x4 acc[4][NREP] = {};

    auto STAGE = [&](int buf, int koff) {
#pragma unroll
        for (int s = 0; s < 2; ++s)
            __builtin_amdgcn_global_load_lds(Ag + a_src[s] + koff,
                                             &As[buf][a_dst[s]], 16, 0, 0);
#pragma unroll
        for (int s = 0; s < BSLOTS; ++s)
            __builtin_amdgcn_global_load_lds(Bg + b_src[s] + koff,
                                             &Bs[buf][b_dst[s]], 16, 0, 0);
    };

    STAGE(0, 0);
    STAGE(1, 32);
    if constexpr (NREP == 4) asm volatile("s_waitcnt vmcnt(4)" ::: "memory");
    else                     asm volatile("s_waitcnt vmcnt(3)" ::: "memory");
    __builtin_amdgcn_s_barrier();
    __builtin_amdgcn_sched_barrier(0);

    const int nK = K >> 5;
    int rd = 0;
    for (int ks = 0; ks < nK; ++ks) {
        const bool st = (ks + 2 < nK);
        if (st) {
            int sb = rd + 2; if (sb >= 3) sb -= 3;
            STAGE(sb, (ks + 2) << 5);
        }
        bf16x8 af[4], bfr[NREP];
#pragma unroll
        for (int m = 0; m < 4; ++m) af[m] = *(const bf16x8*)&As[rd][ra[m]];
#pragma unroll
        for (int n = 0; n < NREP; ++n) bfr[n] = *(const bf16x8*)&Bs[rd][rb[n]];
#pragma unroll
        for (int m = 0; m < 4; ++m)
#pragma unroll
            for (int n = 0; n < NREP; ++n)
                acc[m][n] = MFMA16(af[m], bfr[n], acc[m][n]);
        if (ks + 1 < nK) {
            if (st) {
                if constexpr (NREP == 4) asm volatile("s_waitcnt vmcnt(4)" ::: "memory");
                else                     asm volatile("s_waitcnt vmcnt(3)" ::: "memory");
            } else {
                asm volatile("s_waitcnt vmcnt(0)" ::: "memory");
            }
            __builtin_amdgcn_s_barrier();
            __builtin_amdgcn_sched_barrier(0);
        }
        rd = (rd == 2) ? 0 : rd + 1;
    }

    if (MODE == 0) {
#pragma unroll
        for (int n = 0; n < NREP; ++n) {
            int gn = n0 + wc * WN + n * 16 + lr;
            float bv = bias[gn];
            int s = gn >> 10, hd = gn & 1023;
            int hh = hd >> 6, dd = hd & 63;
            if (s == 2) {
                // V: write transposed -> qkv[2] as [bh][d][t]
                size_t vb = (size_t)2 * 4194304 + (size_t)hh * 131072
                          + (size_t)dd * 2048;
#pragma unroll
                for (int m = 0; m < 4; ++m) {
                    int gm = m0 + wr * 64 + m * 16 + kl * 4;
                    int bb = gm >> 11, tt = gm & 2047;
                    uint64_t p = (uint64_t)f2bf(acc[m][n][0] + bv)
                               | ((uint64_t)f2bf(acc[m][n][1] + bv) << 16)
                               | ((uint64_t)f2bf(acc[m][n][2] + bv) << 32)
                               | ((uint64_t)f2bf(acc[m][n][3] + bv) << 48);
                    *(uint64_t*)(outQKV + vb + (size_t)bb * 2097152 + tt) = p;
                }
            } else {
                // q scale folds 1/sqrt(64) AND log2(e) (attn uses exp2)
                float mult = (s == 0) ? 0.18033688f : 1.0f;
                size_t base = (size_t)s * 4194304 + (size_t)hh * 131072 + dd;
#pragma unroll
                for (int m = 0; m < 4; ++m)
#pragma unroll
                    for (int j = 0; j < 4; ++j) {
                        int gm = m0 + wr * 64 + m * 16 + kl * 4 + j;
                        int bb = gm >> 11, tt = gm & 2047;
                        float val = (acc[m][n][j] + bv) * mult;
                        outQKV[base + (size_t)bb * 2097152 + (size_t)tt * 64] = f2bf(val);
                    }
            }
        }
    } else {
#pragma unroll
        for (int n = 0; n < NREP; ++n) {
            int gn = n0 + wc * WN + n * 16 + lr;
            float bv = bias[gn];
#pragma unroll
            for (int m = 0; m < 4; ++m)
#pragma unroll
                for (int j = 0; j < 4; ++j) {
                    int gm = m0 + wr * 64 + m * 16 + kl * 4 + j;
                    outF[(size_t)gm * N + gn] = acc[m][n][j] + bv;
                }
        }
    }
}

// XCD-aware tile swizzle: grid%8==0, cpx = grid/8; same-XCD blocks share A-panels
__global__ __launch_bounds__(256, 3) void k_gemm_qkv(
    const u16* __restrict__ A, const u16* __restrict__ Bt,
    const float* __restrict__ bias, u16* __restrict__ outQKV,
    int M, int N, int K)
{
    int tile = (blockIdx.x & 7) * (gridDim.x >> 3) + (blockIdx.x >> 3);
    gemm_body<4, 0>(A, Bt, bias, outQKV, nullptr, M, N, tile, K);
}

__global__ __launch_bounds__(256, 3) void k_gemm_proj(
    const u16* __restrict__ A, const u16* __restrict__ Bt,
    const float* __restrict__ bias, float* __restrict__ outF,
    int M, int N, int K)
{
    int tile = (blockIdx.x & 7) * (gridDim.x >> 3) + (blockIdx.x >> 3);
    gemm_body<2, 1>(A, Bt, bias, nullptr, outF, M, N, tile, K);
}

// ---------------- causal flash attention (QBLK=128, 8 waves) ----------------
// r30 change: 128 q-rows per block, 8 waves x 512 threads, grid 512
// (32 bh x 16 q-blocks). Total waves unchanged (4096) but waves/CU
// doubles to 32 (max occupancy), and each staged K/V tile now feeds
// 128 rows -> stage-barrier events per row HALVE. (r28's failure was
// halving wave count; this keeps it constant.)
// S^T trick: MFMA(K, Q) -> col = q = lane's lr, row = key = kl*4+j.
// Q frags direct from global; P = raw v_exp_f32 (log2e folded into q).
// Ps stride 76 u16 (anti-conflict). Causal: mask tiles kt >= nkt-2 with
// the general key>q predicate (lower waves' last tile fully masked -> P=0).
__global__ __launch_bounds__(512, 4) void k_attn(
    const u16* __restrict__ Qg, const u16* __restrict__ Kg,
    const u16* __restrict__ Vtg, u16* __restrict__ Yg)
{
    const int bid = blockIdx.x;
    const int bh = bid & 31;
    const int qt2 = 15 - (bid >> 5);        // 0..15, heavy first
    const int b = bh >> 4, h = bh & 15;
    const int q0 = qt2 << 7;                // 128-row q-block
    const int tid = threadIdx.x, l = tid & 63, w = tid >> 6;   // w: 0..7
    const int kl = l >> 4, lr = l & 15;

    __shared__ __align__(16) u16 Ks[64 * 64];
    __shared__ __align__(16) u16 Vs[64 * 64];
    __shared__ __align__(16) u16 Ps[8][16 * 76];   // per-wave P, stride 76

    const u16* Qb = Qg + (size_t)bh * 131072;
    const u16* Kb = Kg + (size_t)bh * 131072;
    const u16* Vb = Vtg + (size_t)bh * 131072;

    // Q fragments straight from global: row q0+w*16+lr, cols kk*32+kl*8
    bf16x8 qa[2];
#pragma unroll
    for (int kk = 0; kk < 2; ++kk)
        qa[kk] = *(const bf16x8*)(Qb + (size_t)(q0 + w * 16 + lr) * 64
                                  + kk * 32 + kl * 8);

    f32x4 oacc[4] = {};
    float lsum = 0.f;                       // per-lane: q = q0 + w*16 + lr

    // staging: 512 threads cover the 64x64 tile; rr = tid>>3 in [0,64)
    const int rr = tid >> 3, ch = tid & 7;
    bf16x8 kv0 = *(const bf16x8*)(Kb + (size_t)rr * 64 + ch * 8);
    bf16x8 vv0 = *(const bf16x8*)(Vb + (size_t)rr * 2048 + ch * 8);

    const int nkt = 2 * qt2 + 2;            // k-tiles covering keys <= q0+127
    for (int kt = 0; kt < nkt; ++kt) {
        const int k0 = kt << 6;
        __syncthreads();
        *(bf16x8*)&Ks[rr * 64 + ((ch ^ (rr & 7)) << 3)] = kv0;
        *(bf16x8*)&Vs[rr * 64 + ((ch ^ (rr & 7)) << 3)] = vv0;
        __syncthreads();
        if (kt + 1 < nkt) {
            const int k0n = k0 + 64;
            kv0 = *(const bf16x8*)(Kb + (size_t)(k0n + rr) * 64 + ch * 8);
            vv0 = *(const bf16x8*)(Vb + (size_t)rr * 2048 + k0n + ch * 8);
        }

        // S^T = K · Q^T : s[nb][j] = S[key = k0+nb*16+kl*4+j][q = q0+w*16+lr]
        f32x4 s[4];
#pragma unroll
        for (int nb = 0; nb < 4; ++nb) {
            f32x4 a = {};
            int key = nb * 16 + lr;
#pragma unroll
            for (int kk = 0; kk < 2; ++kk) {
                bf16x8 kb = *(const bf16x8*)&Ks[key * 64 + (((kk * 4 + kl) ^ (key & 7)) << 3)];
                a = MFMA16(kb, qa[kk], a);
            }
            s[nb] = a;
        }
        if (kt >= nkt - 2) {   // tiles that can cross any wave's diagonal
            int q = q0 + w * 16 + lr;
#pragma unroll
            for (int nb = 0; nb < 4; ++nb) {
                int keyb = k0 + nb * 16 + kl * 4;
#pragma unroll
                for (int j = 0; j < 4; ++j)
                    if (keyb + j > q) s[nb][j] = -__builtin_inff();
            }
        }
        // P = exp2(S') via raw v_exp_f32; pack 4 consecutive keys -> b64
        float acc16 = 0.f;
#pragma unroll
        for (int nb = 0; nb < 4; ++nb) {
#pragma unroll
            for (int j = 0; j < 4; ++j) {
                s[nb][j] = __builtin_amdgcn_exp2f(s[nb][j]);
                acc16 += s[nb][j];
            }
            uint64_t pk = (uint64_t)cvt_pk_bf16(s[nb][0], s[nb][1])
                        | ((uint64_t)cvt_pk_bf16(s[nb][2], s[nb][3]) << 32);
            *(uint64_t*)&Ps[w][lr * 76 + nb * 16 + kl * 4] = pk;
        }
        lsum += acc16;

        bf16x8 pa[2];
#pragma unroll
        for (int kk = 0; kk < 2; ++kk)
            pa[kk] = *(const bf16x8*)&Ps[w][lr * 76 + kk * 32 + kl * 8];
#pragma unroll
        for (int db = 0; db < 4; ++db) {
            int d = db * 16 + lr;
#pragma unroll
            for (int kk = 0; kk < 2; ++kk) {
                bf16x8 vb = *(const bf16x8*)&Vs[d * 64 + (((kk * 4 + kl) ^ (d & 7)) << 3)];
                oacc[db] = MFMA16(pa[kk], vb, oacc[db]);
            }
        }
    }
    // total per q-row: combine the 4 kl-copies, then redistribute to C-layout rows
    lsum += __shfl_xor(lsum, 16);
    lsum += __shfl_xor(lsum, 32);
    float linv[4];
#pragma unroll
    for (int j = 0; j < 4; ++j)
        linv[j] = 1.f / __shfl(lsum, kl * 4 + j);   // lane kl*4+j holds q-row kl*4+j
#pragma unroll
    for (int db = 0; db < 4; ++db)
#pragma unroll
        for (int j = 0; j < 4; ++j) {
            int q = q0 + w * 16 + kl * 4 + j;
            int col = h * 64 + db * 16 + lr;
            Yg[(size_t)(b * 2048 + q) * 1024 + col] = f2bf(oacc[db][j] * linv[j]);
        }
}

extern "C" void kernel_launch(void* const* d_in, const int* in_sizes, int n_in,
                              void* d_out, int out_size, void* d_ws, size_t ws_size,
                              hipStream_t stream) {
    const float* x     = (const float*)d_in[0];
    const float* Wqkv  = (const float*)d_in[1];
    const float* bqkv  = (const float*)d_in[2];
    const float* Wproj = (const float*)d_in[3];
    const float* bproj = (const float*)d_in[4];
    float* out = (float*)d_out;

    char* ws = (char*)d_ws;
    u16* xb     = (u16*)(ws);                 // 8,388,608 B (x bf16; reused as Yatt)
    u16* WqkvT  = (u16*)(ws + 8388608);       // 6,291,456 B
    u16* WprojT = (u16*)(ws + 14680064);      // 2,097,152 B
    u16* qkv    = (u16*)(ws + 16777216);      // 25,165,824 B : [3][2][16][2048][64]
                                               //   slot 2 holds V TRANSPOSED [bh][d][t]
    u16* Vt   = qkv + 2 * 4194304;             // written directly by k_gemm_qkv
    u16* Yatt = xb;                            // xb free after QKV

    k_prep<<<6144, 256, 0, stream>>>(x, Wqkv, Wproj, xb, WqkvT, WprojT);     // fused prep
    k_gemm_qkv<<<768, 256, 0, stream>>>(xb, WqkvT, bqkv, qkv,
                                        4096, 3072, 1024);                   // qkv (+V^T fused)
    k_attn<<<512, 512, 0, stream>>>(qkv, qkv + 4194304, Vt, Yatt);           // attention (QBLK=128)
    k_gemm_proj<<<512, 256, 0, stream>>>(Yatt, WprojT, bproj, out,
                                         4096, 1024, 1024);                  // projection
}

// Round 32
// 101.815 us; speedup vs baseline: 1.0358x; 1.0358x over previous
//
#include <hip/hip_runtime.h>
#include <hip/hip_bf16.h>
#include <stdint.h>
#include <math.h>

typedef unsigned short u16;
typedef __attribute__((ext_vector_type(8))) short bf16x8;   // 8 bf16 = 4 VGPR MFMA frag
typedef __attribute__((ext_vector_type(4))) float f32x4;    // MFMA accumulator frag

#define MFMA16(a,b,c) __builtin_amdgcn_mfma_f32_16x16x32_bf16((a),(b),(c),0,0,0)

__device__ __forceinline__ u16 f2bf(float f) {
    union { float f; uint32_t u; } v; v.f = f;
    return (u16)((v.u + 0x7FFFu + ((v.u >> 16) & 1u)) >> 16);   // RNE
}

__device__ __forceinline__ uint32_t cvt_pk_bf16(float lo, float hi) {
    uint32_t r;
    asm("v_cvt_pk_bf16_f32 %0, %1, %2" : "=v"(r) : "v"(lo), "v"(hi));
    return r;
}

// ---------- fused prep: x->bf16 | Wqkv^T->bf16 | Wproj^T->bf16 (one dispatch) ----------
__global__ void k_prep(const float* __restrict__ x,
                       const float* __restrict__ Wqkv,
                       const float* __restrict__ Wproj,
                       u16* __restrict__ xb,
                       u16* __restrict__ WqkvT,
                       u16* __restrict__ WprojT)
{
    const int bid = blockIdx.x, tid = threadIdx.x;
    if (bid < 4096) {
        int i = (bid * 256 + tid) * 4;
        f32x4 v = *(const f32x4*)(x + i);
        uint64_t p = (uint64_t)f2bf(v[0]) | ((uint64_t)f2bf(v[1]) << 16)
                   | ((uint64_t)f2bf(v[2]) << 32) | ((uint64_t)f2bf(v[3]) << 48);
        *(uint64_t*)(xb + i) = p;
    } else if (bid < 5632) {
        int id = (bid - 4096) * 256 + tid;
        int n = id % 3072, kc = id / 3072;
        bf16x8 o;
#pragma unroll
        for (int i = 0; i < 8; ++i)
            o[i] = (short)f2bf(Wqkv[(size_t)(kc * 8 + i) * 3072 + n]);
        *(bf16x8*)(WqkvT + (size_t)n * 1024 + kc * 8) = o;
    } else {
        int id = (bid - 5632) * 256 + tid;
        int n = id % 1024, kc = id / 1024;
        bf16x8 o;
#pragma unroll
        for (int i = 0; i < 8; ++i)
            o[i] = (short)f2bf(Wproj[(size_t)(kc * 8 + i) * 1024 + n]);
        *(bf16x8*)(WprojT + (size_t)n * 1024 + kc * 8) = o;
    }
}

// ---------------- bf16 MFMA GEMM body (r10-verified structure) ----------------
// BM=128, BN=32*NREP, BK=32. 4 waves (2x2), wave tile 64 x 16*NREP.
// 3-deep LDS buffers, counted vmcnt (tile k+2 in flight across barrier).
// XOR chunk swizzle on GLOBAL source + ds_read addr (both-sides, LDS linear).
// r22 lesson: NREP=2 QKV doubles A-panel refetch -> NREP=4/768 is optimum.
// MODE 0: scatter to qkv bf16 (q scaled 0.125*log2e); V third TRANSPOSED [bh][d][t].
// MODE 1: fp32 row-major + bias.
template<int NREP, int MODE>
__device__ __forceinline__ void gemm_body(
    const u16* __restrict__ A, const u16* __restrict__ Bt,
    const float* __restrict__ bias,
    u16* __restrict__ outQKV, float* __restrict__ outF,
    int M, int N, int tileId, int K)
{
    constexpr int BN = 32 * NREP;
    constexpr int WN = 16 * NREP;
    constexpr int BSLOTS = NREP / 2;
    __shared__ __align__(16) u16 As[3][128 * 32];
    __shared__ __align__(16) u16 Bs[3][BN * 32];
    const int tid = threadIdx.x;
    const int nbx = N / BN;
    const int bm = tileId / nbx, bn = tileId % nbx;
    const int m0 = bm << 7, n0 = bn * BN;
    const int l = tid & 63, w = tid >> 6;
    const int wr = w >> 1, wc = w & 1;
    const int kl = l >> 4, lr = l & 15;

    const u16* Ag = A + (size_t)m0 * K;
    const u16* Bg = Bt + (size_t)n0 * K;

    int a_src[2], a_dst[2];
#pragma unroll
    for (int s = 0; s < 2; ++s) {
        int cb = w * 128 + s * 64;
        int c = cb + l;
        int r = c >> 2, kc = c & 3;
        a_src[s] = r * K + ((kc ^ ((r >> 1) & 3)) << 3);
        a_dst[s] = cb << 3;
    }
    int b_src[BSLOTS], b_dst[BSLOTS];
#pragma unroll
    for (int s = 0; s < BSLOTS; ++s) {
        int cb = (w * BSLOTS + s) * 64;
        int c = cb + l;
        int r = c >> 2, kc = c & 3;
        b_src[s] = r * K + ((kc ^ ((r >> 1) & 3)) << 3);
        b_dst[s] = cb << 3;
    }

    int ra[4], rb[NREP];
#pragma unroll
    for (int m = 0; m < 4; ++m) {
        int row = wr * 64 + m * 16 + lr;
        ra[m] = row * 32 + (((kl ^ (row >> 1)) & 3) << 3);
    }
#pragma unroll
    for (int n = 0; n < NREP; ++n) {
        int row = wc * WN + n * 16 + lr;
        rb[n] = row * 32 + (((kl ^ (row >> 1)) & 3) << 3);
    }

    f32x4 acc[4][NREP] = {};

    auto STAGE = [&](int buf, int koff) {
#pragma unroll
        for (int s = 0; s < 2; ++s)
            __builtin_amdgcn_global_load_lds(Ag + a_src[s] + koff,
                                             &As[buf][a_dst[s]], 16, 0, 0);
#pragma unroll
        for (int s = 0; s < BSLOTS; ++s)
            __builtin_amdgcn_global_load_lds(Bg + b_src[s] + koff,
                                             &Bs[buf][b_dst[s]], 16, 0, 0);
    };

    STAGE(0, 0);
    STAGE(1, 32);
    if constexpr (NREP == 4) asm volatile("s_waitcnt vmcnt(4)" ::: "memory");
    else                     asm volatile("s_waitcnt vmcnt(3)" ::: "memory");
    __builtin_amdgcn_s_barrier();
    __builtin_amdgcn_sched_barrier(0);

    const int nK = K >> 5;
    int rd = 0;
    for (int ks = 0; ks < nK; ++ks) {
        const bool st = (ks + 2 < nK);
        if (st) {
            int sb = rd + 2; if (sb >= 3) sb -= 3;
            STAGE(sb, (ks + 2) << 5);
        }
        bf16x8 af[4], bfr[NREP];
#pragma unroll
        for (int m = 0; m < 4; ++m) af[m] = *(const bf16x8*)&As[rd][ra[m]];
#pragma unroll
        for (int n = 0; n < NREP; ++n) bfr[n] = *(const bf16x8*)&Bs[rd][rb[n]];
#pragma unroll
        for (int m = 0; m < 4; ++m)
#pragma unroll
            for (int n = 0; n < NREP; ++n)
                acc[m][n] = MFMA16(af[m], bfr[n], acc[m][n]);
        if (ks + 1 < nK) {
            if (st) {
                if constexpr (NREP == 4) asm volatile("s_waitcnt vmcnt(4)" ::: "memory");
                else                     asm volatile("s_waitcnt vmcnt(3)" ::: "memory");
            } else {
                asm volatile("s_waitcnt vmcnt(0)" ::: "memory");
            }
            __builtin_amdgcn_s_barrier();
            __builtin_amdgcn_sched_barrier(0);
        }
        rd = (rd == 2) ? 0 : rd + 1;
    }

    if (MODE == 0) {
#pragma unroll
        for (int n = 0; n < NREP; ++n) {
            int gn = n0 + wc * WN + n * 16 + lr;
            float bv = bias[gn];
            int s = gn >> 10, hd = gn & 1023;
            int hh = hd >> 6, dd = hd & 63;
            if (s == 2) {
                // V: write transposed -> qkv[2] as [bh][d][t]
                size_t vb = (size_t)2 * 4194304 + (size_t)hh * 131072
                          + (size_t)dd * 2048;
#pragma unroll
                for (int m = 0; m < 4; ++m) {
                    int gm = m0 + wr * 64 + m * 16 + kl * 4;
                    int bb = gm >> 11, tt = gm & 2047;
                    uint64_t p = (uint64_t)f2bf(acc[m][n][0] + bv)
                               | ((uint64_t)f2bf(acc[m][n][1] + bv) << 16)
                               | ((uint64_t)f2bf(acc[m][n][2] + bv) << 32)
                               | ((uint64_t)f2bf(acc[m][n][3] + bv) << 48);
                    *(uint64_t*)(outQKV + vb + (size_t)bb * 2097152 + tt) = p;
                }
            } else {
                // q scale folds 1/sqrt(64) AND log2(e) (attn uses exp2)
                float mult = (s == 0) ? 0.18033688f : 1.0f;
                size_t base = (size_t)s * 4194304 + (size_t)hh * 131072 + dd;
#pragma unroll
                for (int m = 0; m < 4; ++m)
#pragma unroll
                    for (int j = 0; j < 4; ++j) {
                        int gm = m0 + wr * 64 + m * 16 + kl * 4 + j;
                        int bb = gm >> 11, tt = gm & 2047;
                        float val = (acc[m][n][j] + bv) * mult;
                        outQKV[base + (size_t)bb * 2097152 + (size_t)tt * 64] = f2bf(val);
                    }
            }
        }
    } else {
#pragma unroll
        for (int n = 0; n < NREP; ++n) {
            int gn = n0 + wc * WN + n * 16 + lr;
            float bv = bias[gn];
#pragma unroll
            for (int m = 0; m < 4; ++m)
#pragma unroll
                for (int j = 0; j < 4; ++j) {
                    int gm = m0 + wr * 64 + m * 16 + kl * 4 + j;
                    outF[(size_t)gm * N + gn] = acc[m][n][j] + bv;
                }
        }
    }
}

// XCD-aware tile swizzle: grid%8==0, cpx = grid/8; same-XCD blocks share A-panels
__global__ __launch_bounds__(256, 3) void k_gemm_qkv(
    const u16* __restrict__ A, const u16* __restrict__ Bt,
    const float* __restrict__ bias, u16* __restrict__ outQKV,
    int M, int N, int K)
{
    int tile = (blockIdx.x & 7) * (gridDim.x >> 3) + (blockIdx.x >> 3);
    gemm_body<4, 0>(A, Bt, bias, outQKV, nullptr, M, N, tile, K);
}

__global__ __launch_bounds__(256, 3) void k_gemm_proj(
    const u16* __restrict__ A, const u16* __restrict__ Bt,
    const float* __restrict__ bias, float* __restrict__ outF,
    int M, int N, int K)
{
    int tile = (blockIdx.x & 7) * (gridDim.x >> 3) + (blockIdx.x >> 3);
    gemm_body<2, 1>(A, Bt, bias, nullptr, outF, M, N, tile, K);
}

// ---------------- causal flash attention (swapped-QK^T softmax) ----------------
// grid 1024: bh = bid&31, qt = 31-(bid>>5); 4 waves x 16 q-rows; Vt is [d][t].
// r28/r31 lessons: pairing (grid 512) and QBLK=128 (8 waves) both regressed —
// QBLK=64 / 4 waves / 1024 blocks is the measured optimum of this class.
// S^T trick: MFMA(K, Q) -> col = q = lane's lr, row = key = kl*4+j.
// Q frags loaded DIRECTLY from global; P = raw v_exp_f32 (log2e in q).
// Ps stride 76 u16 (anti-conflict). (256,4) keeps prefetch in registers.
__global__ __launch_bounds__(256, 4) void k_attn(
    const u16* __restrict__ Qg, const u16* __restrict__ Kg,
    const u16* __restrict__ Vtg, u16* __restrict__ Yg)
{
    const int bid = blockIdx.x;
    const int bh = bid & 31;
    const int qt = 31 - (bid >> 5);
    const int b = bh >> 4, h = bh & 15;
    const int q0 = qt << 6;
    const int tid = threadIdx.x, l = tid & 63, w = tid >> 6;
    const int kl = l >> 4, lr = l & 15;

    __shared__ __align__(16) u16 Ks[64 * 64];
    __shared__ __align__(16) u16 Vs[64 * 64];
    __shared__ __align__(16) u16 Ps[4][16 * 76];   // padded stride 76 (anti-conflict)

    const u16* Qb = Qg + (size_t)bh * 131072;
    const u16* Kb = Kg + (size_t)bh * 131072;
    const u16* Vb = Vtg + (size_t)bh * 131072;

    // Q fragments straight from global: row q0+w*16+lr, cols kk*32+kl*8
    bf16x8 qa[2];
#pragma unroll
    for (int kk = 0; kk < 2; ++kk)
        qa[kk] = *(const bf16x8*)(Qb + (size_t)(q0 + w * 16 + lr) * 64
                                  + kk * 32 + kl * 8);

    f32x4 oacc[4] = {};
    float lsum = 0.f;                       // per-lane: q = q0 + w*16 + lr

    const int rr = tid >> 3, ch = tid & 7;
    bf16x8 kv0 = *(const bf16x8*)(Kb + (size_t)rr * 64 + ch * 8);
    bf16x8 kv1 = *(const bf16x8*)(Kb + (size_t)(rr + 32) * 64 + ch * 8);
    bf16x8 vv0 = *(const bf16x8*)(Vb + (size_t)rr * 2048 + ch * 8);
    bf16x8 vv1 = *(const bf16x8*)(Vb + (size_t)(rr + 32) * 2048 + ch * 8);

    for (int kt = 0; kt <= qt; ++kt) {
        const int k0 = kt << 6;
        __syncthreads();
        *(bf16x8*)&Ks[rr * 64 + ((ch ^ (rr & 7)) << 3)] = kv0;
        *(bf16x8*)&Ks[(rr + 32) * 64 + ((ch ^ (rr & 7)) << 3)] = kv1;
        *(bf16x8*)&Vs[rr * 64 + ((ch ^ (rr & 7)) << 3)] = vv0;
        *(bf16x8*)&Vs[(rr + 32) * 64 + ((ch ^ (rr & 7)) << 3)] = vv1;
        __syncthreads();
        if (kt < qt) {
            const int k0n = k0 + 64;
            kv0 = *(const bf16x8*)(Kb + (size_t)(k0n + rr) * 64 + ch * 8);
            kv1 = *(const bf16x8*)(Kb + (size_t)(k0n + rr + 32) * 64 + ch * 8);
            vv0 = *(const bf16x8*)(Vb + (size_t)rr * 2048 + k0n + ch * 8);
            vv1 = *(const bf16x8*)(Vb + (size_t)(rr + 32) * 2048 + k0n + ch * 8);
        }

        // S^T = K · Q^T : s[nb][j] = S[key = k0+nb*16+kl*4+j][q = q0+w*16+lr]
        f32x4 s[4];
#pragma unroll
        for (int nb = 0; nb < 4; ++nb) {
            f32x4 a = {};
            int key = nb * 16 + lr;
#pragma unroll
            for (int kk = 0; kk < 2; ++kk) {
                bf16x8 kb = *(const bf16x8*)&Ks[key * 64 + (((kk * 4 + kl) ^ (key & 7)) << 3)];
                a = MFMA16(kb, qa[kk], a);
            }
            s[nb] = a;
        }
        if (kt == qt) {   // diagonal: mask key > q
            int q = q0 + w * 16 + lr;
#pragma unroll
            for (int nb = 0; nb < 4; ++nb) {
                int keyb = k0 + nb * 16 + kl * 4;
#pragma unroll
                for (int j = 0; j < 4; ++j)
                    if (keyb + j > q) s[nb][j] = -__builtin_inff();
            }
        }
        // P = exp2(S') via raw v_exp_f32; pack 4 consecutive keys -> b64
        float acc16 = 0.f;
#pragma unroll
        for (int nb = 0; nb < 4; ++nb) {
#pragma unroll
            for (int j = 0; j < 4; ++j) {
                s[nb][j] = __builtin_amdgcn_exp2f(s[nb][j]);
                acc16 += s[nb][j];
            }
            uint64_t pk = (uint64_t)cvt_pk_bf16(s[nb][0], s[nb][1])
                        | ((uint64_t)cvt_pk_bf16(s[nb][2], s[nb][3]) << 32);
            *(uint64_t*)&Ps[w][lr * 76 + nb * 16 + kl * 4] = pk;
        }
        lsum += acc16;

        bf16x8 pa[2];
#pragma unroll
        for (int kk = 0; kk < 2; ++kk)
            pa[kk] = *(const bf16x8*)&Ps[w][lr * 76 + kk * 32 + kl * 8];
#pragma unroll
        for (int db = 0; db < 4; ++db) {
            int d = db * 16 + lr;
#pragma unroll
            for (int kk = 0; kk < 2; ++kk) {
                bf16x8 vb = *(const bf16x8*)&Vs[d * 64 + (((kk * 4 + kl) ^ (d & 7)) << 3)];
                oacc[db] = MFMA16(pa[kk], vb, oacc[db]);
            }
        }
    }
    // total per q-row: combine the 4 kl-copies, then redistribute to C-layout rows
    lsum += __shfl_xor(lsum, 16);
    lsum += __shfl_xor(lsum, 32);
    float linv[4];
#pragma unroll
    for (int j = 0; j < 4; ++j)
        linv[j] = 1.f / __shfl(lsum, kl * 4 + j);   // lane kl*4+j holds q-row kl*4+j
#pragma unroll
    for (int db = 0; db < 4; ++db)
#pragma unroll
        for (int j = 0; j < 4; ++j) {
            int q = q0 + w * 16 + kl * 4 + j;
            int col = h * 64 + db * 16 + lr;
            Yg[(size_t)(b * 2048 + q) * 1024 + col] = f2bf(oacc[db][j] * linv[j]);
        }
}

extern "C" void kernel_launch(void* const* d_in, const int* in_sizes, int n_in,
                              void* d_out, int out_size, void* d_ws, size_t ws_size,
                              hipStream_t stream) {
    const float* x     = (const float*)d_in[0];
    const float* Wqkv  = (const float*)d_in[1];
    const float* bqkv  = (const float*)d_in[2];
    const float* Wproj = (const float*)d_in[3];
    const float* bproj = (const float*)d_in[4];
    float* out = (float*)d_out;

    char* ws = (char*)d_ws;
    u16* xb     = (u16*)(ws);                 // 8,388,608 B (x bf16; reused as Yatt)
    u16* WqkvT  = (u16*)(ws + 8388608);       // 6,291,456 B
    u16* WprojT = (u16*)(ws + 14680064);      // 2,097,152 B
    u16* qkv    = (u16*)(ws + 16777216);      // 25,165,824 B : [3][2][16][2048][64]
                                               //   slot 2 holds V TRANSPOSED [bh][d][t]
    u16* Vt   = qkv + 2 * 4194304;             // written directly by k_gemm_qkv
    u16* Yatt = xb;                            // xb free after QKV

    k_prep<<<6144, 256, 0, stream>>>(x, Wqkv, Wproj, xb, WqkvT, WprojT);     // fused prep
    k_gemm_qkv<<<768, 256, 0, stream>>>(xb, WqkvT, bqkv, qkv,
                                        4096, 3072, 1024);                   // qkv (+V^T fused)
    k_attn<<<1024, 256, 0, stream>>>(qkv, qkv + 4194304, Vt, Yatt);          // attention
    k_gemm_proj<<<512, 256, 0, stream>>>(Yatt, WprojT, bproj, out,
                                         4096, 1024, 1024);                  // projection
}